// Round 12
// baseline (519.153 us; speedup 1.0000x reference)
//
#include <hip/hip_runtime.h>
#include <math.h>

// FieldFormer fused kernel, round 15 = round 11 EXACT resubmission (519us, passing).
// r12-r14 post-mortem: pairwise bf16 HW conversion fails regardless of form
// (intrinsic __float22bfloat162_rn: 0.0273; raw v_cvt_pk_bf16_f32 asm: 0.0322)
// while the single-operand asm form passed (r8) and software RNE passes always.
// Mechanism unresolved (half-mapping vs rounding, indistinguishable with equal
// operands; r8's plateau-exact absmax can mask sub-ulp drift). Per rigor rules,
// unexplained => not shippable. FROZEN: software f2bf, gelu A&S 7.1.26.
// Structure: quarter-split GEMM1/GEMM2 (LDS 27136 -> 6 blocks/CU, occ 65%),
// pool fused into GEMM2 epilogue -> global, head split into M=64 MFMA kernel.
// Main kernel sits at the VALU-issue roofline: VALUBusy 90.3% + MfmaUtil 13.1%.
#define KN 32
#define DD 128
#define FF 256
#define QB 2
#define MROWS (QB * KN)      // 64
#define HP 136               // s_hA pitch (ushort), 128+8
#define XQP 72               // s_x quarter pitch (ushort), 64+8
#define RP 264               // head_kernel s_A pitch (ushort), 256+8

typedef __attribute__((ext_vector_type(8))) short bf16x8;
typedef __attribute__((ext_vector_type(4))) float f32x4;

__device__ __forceinline__ unsigned short f2bf(float x) {
    union { float f; unsigned u; } c; c.f = x;
    unsigned r = c.u + 0x7fffu + ((c.u >> 16) & 1u);   // RNE
    return (unsigned short)(r >> 16);
}
__device__ __forceinline__ float bf2f(unsigned short h) {
    union { unsigned u; float f; } c; c.u = ((unsigned)h) << 16;
    return c.f;
}

// gelu(x) = 0.5*x*(1+erf(x/sqrt2)), erf via A&S 7.1.26 (|err|<=1.5e-7). FROZEN.
__device__ __forceinline__ float gelu_f(float x) {
    float z  = __builtin_fabsf(x) * 0.70710678118654752440f;
    float z2 = z * z;
    float e  = __builtin_amdgcn_exp2f(z2 * -1.4426950408889634f);   // exp(-z^2)
    float t  = __builtin_amdgcn_rcpf(fmaf(0.3275911f, z, 1.0f));
    float p  = fmaf(1.061405429f, t, -1.453152027f);
    p = fmaf(p, t, 1.421413741f);
    p = fmaf(p, t, -0.284496736f);
    p = fmaf(p, t, 0.254829592f);
    p = p * t;
    float erfz = fmaf(-p, e, 1.0f);                 // erf(|x|/sqrt2)
    float erfs = (x < 0.0f) ? -erfz : erfz;
    float hx = 0.5f * x;
    return fmaf(hx, erfs, hx);
}

// Prep: w1 [256,128] -> bf16, w2 [128,256] -> bf16, hw1 [256,256] -> bf16.
__global__ void prep_kernel(const float* __restrict__ w1,
                            const float* __restrict__ w2,
                            const float* __restrict__ hw1,
                            unsigned short* __restrict__ w1b,
                            unsigned short* __restrict__ w2b,
                            unsigned short* __restrict__ hw1b) {
    int i = blockIdx.x * 256 + threadIdx.x;   // 0..65535
    hw1b[i] = f2bf(hw1[i]);
    if (i < 32768) {
        w1b[i] = f2bf(w1[i]);
        w2b[i] = f2bf(w2[i]);
    }
}

__launch_bounds__(256, 6)
__global__ void ff_mfma_kernel(
    const float* __restrict__ xyt_q,
    const float* __restrict__ obs_coords,
    const float* __restrict__ obs_vals,
    const int*   __restrict__ nb_idx,
    const float* __restrict__ log_gammas,
    const float* __restrict__ w_in,   // [128,4]
    const float* __restrict__ b_in,
    const float* __restrict__ ln1_g,
    const float* __restrict__ ln1_b,
    const unsigned short* __restrict__ w1b,  // [256,128] bf16
    const float* __restrict__ b1,
    const unsigned short* __restrict__ w2b,  // [128,256] bf16
    const float* __restrict__ b2,
    float* __restrict__ pooled,   // [Q][256] f32 out
    float* __restrict__ musig)    // [Q][2]   f32 out
{
    __shared__ __align__(16) unsigned short s_hA[MROWS * HP];      // 17408: h_ln
    __shared__ __align__(16) unsigned char  s_xb[MROWS * XQP * 2]; // 9216: x quarter / tokf alias
    __shared__ float s_mu[QB], s_sig[QB];

    unsigned short* s_x = (unsigned short*)s_xb;
    float (*s_tokf)[4]  = (float(*)[4])s_xb;     // phase 0-1 only (dead before 1st s_x write)

    const int t    = threadIdx.x;
    const int lane = t & 63;
    const int wv   = t >> 6;
    const int m16  = lane & 15;
    const int quad = lane >> 4;
    const int q0   = blockIdx.x * QB;

    // ---- Phase 0: gather neighbors, tokens, mu/sigma (ddof=1, clip 1e-3) ----
    if (t < MROWS) {
        int qi = t >> 5, j = t & 31;
        int q = q0 + qi;
        int idx = nb_idx[q * KN + j];
        float v = obs_vals[idx];
        float g0 = expf(log_gammas[0]), g1 = expf(log_gammas[1]), g2 = expf(log_gammas[2]);
        s_tokf[t][0] = (obs_coords[idx * 3 + 0] - xyt_q[q * 3 + 0]) * g0;
        s_tokf[t][1] = (obs_coords[idx * 3 + 1] - xyt_q[q * 3 + 1]) * g1;
        s_tokf[t][2] = (obs_coords[idx * 3 + 2] - xyt_q[q * 3 + 2]) * g2;
        float s = v, ss = v * v;
        #pragma unroll
        for (int m = 1; m < 32; m <<= 1) {
            s  += __shfl_xor(s, m);
            ss += __shfl_xor(ss, m);
        }
        float mu  = s * (1.0f / KN);
        float var = (ss - (float)KN * mu * mu) * (1.0f / (KN - 1));
        float sig = fmaxf(sqrtf(fmaxf(var, 0.0f)), 1e-3f);
        if (j == 0) { s_mu[qi] = mu; s_sig[qi] = sig; }
        s_tokf[t][3] = (v - mu) / sig;
    }
    __syncthreads();

    // ---- Phase 1+2 fused: h = gelu(tok @ w_in^T + b_in), LN over 128 -> bf16 s_hA.
    {
        float4 wlo = ((const float4*)w_in)[lane];
        float4 whi = ((const float4*)w_in)[lane + 64];
        float blo = b_in[lane],  bhi = b_in[lane + 64];
        float glo = ln1_g[lane], ghi = ln1_g[lane + 64];
        float clo = ln1_b[lane], chi = ln1_b[lane + 64];
        #pragma unroll
        for (int i = 0; i < 16; i++) {
            int tok = wv * 16 + i;
            float4 tk = *(const float4*)&s_tokf[tok][0];
            float a0 = fmaf(wlo.x, tk.x, fmaf(wlo.y, tk.y, fmaf(wlo.z, tk.z, fmaf(wlo.w, tk.w, blo))));
            float a1 = fmaf(whi.x, tk.x, fmaf(whi.y, tk.y, fmaf(whi.z, tk.z, fmaf(whi.w, tk.w, bhi))));
            float v0 = gelu_f(a0), v1 = gelu_f(a1);
            float s = v0 + v1, ss = v0 * v0 + v1 * v1;
            #pragma unroll
            for (int m = 1; m < 64; m <<= 1) {
                s  += __shfl_xor(s, m);
                ss += __shfl_xor(ss, m);
            }
            float mean = s * (1.0f / DD);
            float var  = ss * (1.0f / DD) - mean * mean;
            float rstd = rsqrtf(fmaxf(var, 0.0f) + 1e-5f);
            s_hA[tok * HP + lane]      = f2bf((v0 - mean) * rstd * glo + clo);
            s_hA[tok * HP + 64 + lane] = f2bf((v1 - mean) * rstd * ghi + chi);
        }
    }
    __syncthreads();   // also retires s_tokf before s_x overwrites it

    // ---- Phases 3+4 quarter-split: per quarter qd, GEMM1 emits x cols
    //      [qd*64, qd*64+64) into s_x (wave strip = 16 cols), then GEMM2
    //      accumulates k=qd*64..+63 into persistent acc2 (global kk order
    //      0..7 preserved -> bit-identical to the half-split).
    f32x4 acc2[4][2];
    #pragma unroll
    for (int rt = 0; rt < 4; rt++)
        #pragma unroll
        for (int ct = 0; ct < 2; ct++)
            acc2[rt][ct] = (f32x4){0.f, 0.f, 0.f, 0.f};

    #pragma unroll
    for (int qd = 0; qd < 4; qd++) {
        // GEMM1 quarter: x[:, qd*64 + wv*16 + m16] = gelu(hln @ w1^T + b1)
        {
            const int gcol = qd * 64 + wv * 16 + m16;
            bf16x8 B[4];
            #pragma unroll
            for (int kk = 0; kk < 4; kk++)
                B[kk] = *(const bf16x8*)&w1b[gcol * 128 + kk * 32 + quad * 8];
            float bb = b1[gcol];
            #pragma unroll
            for (int rt = 0; rt < 4; rt++) {
                bf16x8 A[4];
                #pragma unroll
                for (int kk = 0; kk < 4; kk++)
                    A[kk] = *(const bf16x8*)&s_hA[(rt * 16 + m16) * HP + kk * 32 + quad * 8];
                f32x4 acc = {0.f, 0.f, 0.f, 0.f};
                #pragma unroll
                for (int kk = 0; kk < 4; kk++)
                    acc = __builtin_amdgcn_mfma_f32_16x16x32_bf16(A[kk], B[kk], acc, 0, 0, 0);
                #pragma unroll
                for (int r = 0; r < 4; r++)
                    s_x[(rt * 16 + quad * 4 + r) * XQP + wv * 16 + m16] = f2bf(gelu_f(acc[r] + bb));
            }
        }
        __syncthreads();
        // GEMM2 partial: acc2 += x_quarter @ w2[:, qd*64 .. qd*64+63]^T
        {
            bf16x8 B2[2][2];
            #pragma unroll
            for (int ct = 0; ct < 2; ct++)
                #pragma unroll
                for (int k2 = 0; k2 < 2; k2++)
                    B2[ct][k2] = *(const bf16x8*)&w2b[(wv * 32 + ct * 16 + m16) * 256 + qd * 64 + k2 * 32 + quad * 8];
            #pragma unroll
            for (int rt = 0; rt < 4; rt++) {
                bf16x8 A2[2];
                #pragma unroll
                for (int k2 = 0; k2 < 2; k2++)
                    A2[k2] = *(const bf16x8*)&s_x[(rt * 16 + m16) * XQP + k2 * 32 + quad * 8];
                #pragma unroll
                for (int ct = 0; ct < 2; ct++)
                    #pragma unroll
                    for (int k2 = 0; k2 < 2; k2++)
                        acc2[rt][ct] = __builtin_amdgcn_mfma_f32_16x16x32_bf16(A2[k2], B2[ct][k2], acc2[rt][ct], 0, 0, 0);
            }
        }
        if (qd < 3) __syncthreads();   // before next GEMM1 overwrites s_x
    }

    // ---- Fused GEMM2 epilogue + pool: h2 rows live in acc2 (row = rt*16+quad*4+r;
    //      rt 0,1 = query 0, rt 2,3 = query 1). gelu, mean/max over 8 in-register
    //      rows + quad shfl_xor 16/32 -> full 32-row pool per col -> global.
    {
        const float inv = 1.0f / KN;
        #pragma unroll
        for (int ct = 0; ct < 2; ct++) {
            int col = wv * 32 + ct * 16 + m16;
            float bb = b2[col];
            float sm0 = 0.f, mx0 = -INFINITY, sm1 = 0.f, mx1 = -INFINITY;
            #pragma unroll
            for (int r = 0; r < 4; r++) {
                float g0 = gelu_f(acc2[0][ct][r] + bb);
                float g1 = gelu_f(acc2[1][ct][r] + bb);
                float g2 = gelu_f(acc2[2][ct][r] + bb);
                float g3 = gelu_f(acc2[3][ct][r] + bb);
                sm0 += g0 + g1; mx0 = fmaxf(mx0, fmaxf(g0, g1));
                sm1 += g2 + g3; mx1 = fmaxf(mx1, fmaxf(g2, g3));
            }
            sm0 += __shfl_xor(sm0, 16); mx0 = fmaxf(mx0, __shfl_xor(mx0, 16));
            sm0 += __shfl_xor(sm0, 32); mx0 = fmaxf(mx0, __shfl_xor(mx0, 32));
            sm1 += __shfl_xor(sm1, 16); mx1 = fmaxf(mx1, __shfl_xor(mx1, 16));
            sm1 += __shfl_xor(sm1, 32); mx1 = fmaxf(mx1, __shfl_xor(mx1, 32));
            if (quad == 0) {
                pooled[(q0 + 0) * 256 + col]       = sm0 * inv;
                pooled[(q0 + 0) * 256 + 128 + col] = mx0;
                pooled[(q0 + 1) * 256 + col]       = sm1 * inv;
                pooled[(q0 + 1) * 256 + 128 + col] = mx1;
            }
        }
    }
    if (t < QB) {
        musig[(q0 + t) * 2 + 0] = s_mu[t];
        musig[(q0 + t) * 2 + 1] = s_sig[t];
    }
}

// Head: per 64 queries, LN over 256 -> bf16 A, then hidden = gelu(A @ hw1^T + hb1),
// out = (hidden . hw2) + hb2, rescale by mu/sigma. M=64 MFMA GEMM.
__launch_bounds__(256, 2)
__global__ void head_kernel(
    const float* __restrict__ pooled,        // [Q][256]
    const float* __restrict__ musig,         // [Q][2]
    const unsigned short* __restrict__ hw1b, // [256,256] bf16
    const float* __restrict__ hln_g,
    const float* __restrict__ hln_b,
    const float* __restrict__ hb1,
    const float* __restrict__ hw2,
    const float* __restrict__ hb2,
    float* __restrict__ out)
{
    __shared__ __align__(16) unsigned short s_A[64 * RP];  // 33792 B
    __shared__ float s_part[4][64];

    const int t    = threadIdx.x;
    const int lane = t & 63;
    const int wv   = t >> 6;
    const int m16  = lane & 15;
    const int quad = lane >> 4;
    const int r0   = blockIdx.x * 64;

    // ---- head LN over 256 per row (wave wv: rows wv*16..+15) -> bf16 s_A ----
    {
        float g0 = hln_g[lane], g1 = hln_g[lane + 64], g2 = hln_g[lane + 128], g3 = hln_g[lane + 192];
        float c0 = hln_b[lane], c1 = hln_b[lane + 64], c2 = hln_b[lane + 128], c3 = hln_b[lane + 192];
        for (int i = 0; i < 16; i++) {
            int row = wv * 16 + i;
            const float* pr = &pooled[(r0 + row) * 256];
            float v0 = pr[lane], v1 = pr[lane + 64], v2 = pr[lane + 128], v3 = pr[lane + 192];
            float s = v0 + v1 + v2 + v3;
            float ss = v0 * v0 + v1 * v1 + v2 * v2 + v3 * v3;
            #pragma unroll
            for (int m = 1; m < 64; m <<= 1) {
                s  += __shfl_xor(s, m);
                ss += __shfl_xor(ss, m);
            }
            float mean = s * (1.0f / 256.0f);
            float var  = ss * (1.0f / 256.0f) - mean * mean;
            float rstd = rsqrtf(fmaxf(var, 0.0f) + 1e-5f);
            s_A[row * RP + lane]       = f2bf((v0 - mean) * rstd * g0 + c0);
            s_A[row * RP + lane + 64]  = f2bf((v1 - mean) * rstd * g1 + c1);
            s_A[row * RP + lane + 128] = f2bf((v2 - mean) * rstd * g2 + c2);
            s_A[row * RP + lane + 192] = f2bf((v3 - mean) * rstd * g3 + c3);
        }
    }
    __syncthreads();

    // ---- GEMM [64,256]x[256,256]^T, fused gelu*hw2 row-sum. ----
    {
        float ps[4][4];
        #pragma unroll
        for (int rt = 0; rt < 4; rt++)
            #pragma unroll
            for (int r = 0; r < 4; r++)
                ps[rt][r] = 0.f;
        #pragma unroll
        for (int ct = 0; ct < 4; ct++) {
            int col = wv * 64 + ct * 16 + m16;
            bf16x8 Bf[8];
            #pragma unroll
            for (int kk = 0; kk < 8; kk++)
                Bf[kk] = *(const bf16x8*)&hw1b[col * 256 + kk * 32 + quad * 8];
            float bb = hb1[col], w2v = hw2[col];
            #pragma unroll
            for (int rt = 0; rt < 4; rt++) {
                bf16x8 A[8];
                #pragma unroll
                for (int kk = 0; kk < 8; kk++)
                    A[kk] = *(const bf16x8*)&s_A[(rt * 16 + m16) * RP + kk * 32 + quad * 8];
                f32x4 acc = {0.f, 0.f, 0.f, 0.f};
                #pragma unroll
                for (int kk = 0; kk < 8; kk++)
                    acc = __builtin_amdgcn_mfma_f32_16x16x32_bf16(A[kk], Bf[kk], acc, 0, 0, 0);
                #pragma unroll
                for (int r = 0; r < 4; r++)
                    ps[rt][r] = fmaf(gelu_f(acc[r] + bb), w2v, ps[rt][r]);
            }
        }
        // reduce partial row-sums over the 16 m16 lanes
        #pragma unroll
        for (int rt = 0; rt < 4; rt++)
            #pragma unroll
            for (int r = 0; r < 4; r++) {
                float v = ps[rt][r];
                #pragma unroll
                for (int m = 1; m < 16; m <<= 1)
                    v += __shfl_xor(v, m);
                if (m16 == 0) s_part[wv][rt * 16 + quad * 4 + r] = v;
            }
    }
    __syncthreads();
    if (t < 64) {
        float u = s_part[0][t] + s_part[1][t] + s_part[2][t] + s_part[3][t] + hb2[0];
        int q = r0 + t;
        out[q] = u * musig[q * 2 + 1] + musig[q * 2 + 0];
    }
}

extern "C" void kernel_launch(void* const* d_in, const int* in_sizes, int n_in,
                              void* d_out, int out_size, void* d_ws, size_t ws_size,
                              hipStream_t stream)
{
    const float* xyt_q      = (const float*)d_in[0];
    const float* obs_coords = (const float*)d_in[1];
    const float* obs_vals   = (const float*)d_in[2];
    const int*   nb_idx     = (const int*)d_in[3];
    const float* log_gammas = (const float*)d_in[4];
    const float* w_in  = (const float*)d_in[5];
    const float* b_in  = (const float*)d_in[6];
    const float* ln1_g = (const float*)d_in[7];
    const float* ln1_b = (const float*)d_in[8];
    const float* w1    = (const float*)d_in[9];
    const float* b1    = (const float*)d_in[10];
    const float* w2    = (const float*)d_in[11];
    const float* b2    = (const float*)d_in[12];
    const float* hln_g = (const float*)d_in[13];
    const float* hln_b = (const float*)d_in[14];
    const float* hw1   = (const float*)d_in[15];
    const float* hb1   = (const float*)d_in[16];
    const float* hw2   = (const float*)d_in[17];
    const float* hb2   = (const float*)d_in[18];
    float* out = (float*)d_out;

    const int Q = in_sizes[0] / 3;   // 32768

    // workspace layout
    unsigned short* w1b  = (unsigned short*)d_ws;                       //   0 .. 64KB
    unsigned short* w2b  = w1b + 32768;                                 //  64 .. 128KB
    unsigned short* hw1b = (unsigned short*)((char*)d_ws + 131072);     // 128 .. 256KB
    float*          musig  = (float*)((char*)d_ws + 262144);            // 256 .. 512KB
    float*          pooled = (float*)((char*)d_ws + 524288);            // 512KB .. +32MB

    prep_kernel<<<256, 256, 0, stream>>>(w1, w2, hw1, w1b, w2b, hw1b);

    ff_mfma_kernel<<<Q / QB, 256, 0, stream>>>(
        xyt_q, obs_coords, obs_vals, nb_idx, log_gammas,
        w_in, b_in, ln1_g, ln1_b,
        w1b, b1, w2b, b2,
        pooled, musig);

    head_kernel<<<Q / 64, 256, 0, stream>>>(
        pooled, musig, hw1b, hln_g, hln_b, hb1, hw2, hb2, out);
}